// Round 6
// baseline (603.146 us; speedup 1.0000x reference)
//
#include <hip/hip_runtime.h>
#include <hip/hip_bf16.h>
#include <cstdint>

#define T_TOK 8192
#define DDIM 1024
#define FDIM 4096
#define NEXP 8
#define MAX_TILES 40  // 256-row tiles: sum ceil(counts[e]/256) <= 32+7 = 39

typedef short short8 __attribute__((ext_vector_type(8)));
typedef float floatx4 __attribute__((ext_vector_type(4)));

// round-to-nearest-even f32 -> bf16
__device__ __forceinline__ short f2bf(float f) {
  unsigned u = __float_as_uint(f);
  unsigned r = (u + 0x7fffu + ((u >> 16) & 1u)) >> 16;
  return (short)r;
}

// async global -> LDS, 16B per lane (dest = wave-uniform base + lane*16)
__device__ __forceinline__ void load_lds16(const void* g, void* l) {
  __builtin_amdgcn_global_load_lds(
      (__attribute__((address_space(1))) unsigned int*)g,
      (__attribute__((address_space(3))) unsigned int*)l, 16, 0, 0);
}

// ---------------- router: one wave per token, NO atomics ----------------
// Fuses x -> bf16 conversion (token-ordered Xbf); expert-sort is virtual via
// tok_of_row indirection in FFN1 staging.
__global__ __launch_bounds__(256) void router_kernel(
    const float* __restrict__ x, const float* __restrict__ rw,
    const float* __restrict__ rb, int* __restrict__ expert_t,
    float* __restrict__ gate_t, short* __restrict__ Xbf) {
  __shared__ float w[NEXP * DDIM];  // 32 KiB
  int tid = threadIdx.x;
  for (int i = tid; i < NEXP * DDIM; i += 256) w[i] = rw[i];
  __syncthreads();
  int wid = tid >> 6, lane = tid & 63;
  int t = blockIdx.x * 4 + wid;
  const float4* xr = (const float4*)(x + (size_t)t * DDIM);
  uint2* xd = (uint2*)(Xbf + (size_t)t * DDIM);
  float acc[NEXP];
#pragma unroll
  for (int e = 0; e < NEXP; e++) acc[e] = 0.f;
#pragma unroll
  for (int i = 0; i < 4; i++) {
    float4 v = xr[lane + 64 * i];
    uint2 p;
    p.x = (unsigned)(unsigned short)f2bf(v.x) |
          ((unsigned)(unsigned short)f2bf(v.y) << 16);
    p.y = (unsigned)(unsigned short)f2bf(v.z) |
          ((unsigned)(unsigned short)f2bf(v.w) << 16);
    xd[lane + 64 * i] = p;
    int col = (lane + 64 * i) * 4;
#pragma unroll
    for (int e = 0; e < NEXP; e++) {
      const float4 wv = *(const float4*)&w[e * DDIM + col];
      acc[e] += v.x * wv.x + v.y * wv.y + v.z * wv.z + v.w * wv.w;
    }
  }
#pragma unroll
  for (int e = 0; e < NEXP; e++) {
#pragma unroll
    for (int off = 32; off > 0; off >>= 1) acc[e] += __shfl_xor(acc[e], off);
  }
  if (lane == 0) {
    float l[NEXP];
#pragma unroll
    for (int e = 0; e < NEXP; e++) l[e] = acc[e] + rb[e];
    int best = 0;
    float lm = l[0];
#pragma unroll
    for (int e = 1; e < NEXP; e++)
      if (l[e] > lm) { lm = l[e]; best = e; }
    float s = 0.f;
#pragma unroll
    for (int e = 0; e < NEXP; e++) s += expf(l[e] - lm);
    expert_t[t] = best;
    gate_t[t] = 1.f / s;  // softmax prob of argmax
  }
}

// ------- finalize: one block, 4 waves; wave w owns tokens [2048w, 2048w+2048)
// Ballot histograms + scan -> counts/offsets/positions, probsum, aux loss,
// tile list, and the tok_of_row / gate_row scatter. Small (~64KB r/w).
__global__ __launch_bounds__(256) void finalize_kernel(
    const int* __restrict__ expert_t, const float* __restrict__ gate_t,
    int* __restrict__ counts, int* __restrict__ offsets,
    float* __restrict__ loss_out, int* __restrict__ tileE,
    int* __restrict__ tileM, int* __restrict__ ntiles,
    int* __restrict__ tok_of_row, float* __restrict__ gate_row) {
  __shared__ int wcnt_s[4 * NEXP];
  __shared__ float wps_s[4 * NEXP];
  __shared__ int wbase_s[4 * NEXP];
  __shared__ int offs_s[NEXP];
  int tid = threadIdx.x;
  int wid = tid >> 6, lane = tid & 63;
  unsigned long long lt = (1ull << lane) - 1ull;
  int cnt[NEXP];
  float ps[NEXP];
#pragma unroll
  for (int e = 0; e < NEXP; e++) {
    cnt[e] = 0;
    ps[e] = 0.f;
  }
  int tbase = wid * 2048;
  for (int c = 0; c < 32; c++) {
    int t = tbase + c * 64 + lane;
    int ex = expert_t[t];
    float g = gate_t[t];
#pragma unroll
    for (int e = 0; e < NEXP; e++) {
      unsigned long long b = __ballot(ex == e);
      cnt[e] += __popcll(b);
      float v = (ex == e) ? g : 0.f;
#pragma unroll
      for (int off = 32; off > 0; off >>= 1) v += __shfl_xor(v, off);
      ps[e] += v;  // butterfly: all lanes hold the sum
    }
  }
  if (lane == 0) {
#pragma unroll
    for (int e = 0; e < NEXP; e++) {
      wcnt_s[wid * NEXP + e] = cnt[e];
      wps_s[wid * NEXP + e] = ps[e];
    }
  }
  __syncthreads();
  if (tid < NEXP) {
    int run = 0;
    for (int w = 0; w < 4; w++) {
      wbase_s[w * NEXP + tid] = run;
      run += wcnt_s[w * NEXP + tid];
    }
    counts[tid] = run;
  }
  __syncthreads();
  if (tid == 0) {
    int off = 0, nt = 0;
    float loss = 0.f;
    for (int e = 0; e < NEXP; e++) {
      int cn = counts[e];
      offsets[e] = off;
      offs_s[e] = off;
      float psum = wps_s[0 * NEXP + e] + wps_s[1 * NEXP + e] +
                   wps_s[2 * NEXP + e] + wps_s[3 * NEXP + e];
      loss += ((float)cn / (float)T_TOK) *
              (psum / ((float)T_TOK * (float)T_TOK));
      off += cn;
      for (int m = 0; m < cn; m += 256) {
        tileE[nt] = e;
        tileM[nt] = m;
        nt++;
      }
    }
    offsets[NEXP] = off;
    *ntiles = nt;
    *loss_out = loss * 3e-6f * (float)NEXP;
  }
  __syncthreads();
  // pass 2: positions + scatter (per-wave independent)
  int runl[NEXP];
#pragma unroll
  for (int e = 0; e < NEXP; e++) runl[e] = 0;
  for (int c = 0; c < 32; c++) {
    int t = tbase + c * 64 + lane;
    int ex = expert_t[t];
    int pre = 0;
#pragma unroll
    for (int e = 0; e < NEXP; e++) {
      unsigned long long b = __ballot(ex == e);
      if (ex == e) pre = __popcll(b & lt) + runl[e];
      runl[e] += __popcll(b);
    }
    int row = offs_s[ex] + wbase_s[wid * NEXP + ex] + pre;
    tok_of_row[row] = t;
    gate_row[row] = gate_t[t];
  }
}

// ---------------- 256x256 bf16 GEMM with fused B transpose+convert ---------
// B is read DIRECTLY from w1/w2 f32 [k][n] (no pre-transpose pass): per
// K-tile each thread loads 8x float4 from 8 k-rows, transposes in registers
// via v_cvt_pk_bf16_f32, and ds_write_b128's the XOR-swizzled [n][k] tile.
// A stays on global_load_lds (swizzled source). Counted-vmcnt schedule,
// 1 barrier per K-tile, vmcnt never drains to 0 mid-loop:
//   top:  issue Breg(t+1)[8] ; vmcnt(8) drains A(t), keeps Breg ; lgkm(0)
//   s_barrier ; issue A-gld(t+1)[4] ; 4x phase_mfma(t)
//   bottom: vmcnt(4) drains Breg, keeps A-gld ; cvt + ds_write B(t+1)
template <int MH, int NH>
__device__ __forceinline__ void phase_mfma(const char* Ab, const char* Bb,
                                           floatx4 (&acc)[8][4], int wm,
                                           int wn, int lane) {
  int l15 = lane & 15, quad = lane >> 4, low3 = lane & 7;
  short8 af[4][2], bv[2][2];
#pragma unroll
  for (int i = 0; i < 4; i++) {
    int row = MH * 128 + wm * 64 + i * 16 + l15;
#pragma unroll
    for (int ks = 0; ks < 2; ks++)
      af[i][ks] =
          *(const short8*)(Ab + row * 128 + (((ks * 4 + quad) ^ low3) << 4));
  }
#pragma unroll
  for (int j = 0; j < 2; j++) {
    int col = NH * 128 + wn * 32 + j * 16 + l15;
#pragma unroll
    for (int ks = 0; ks < 2; ks++)
      bv[j][ks] =
          *(const short8*)(Bb + col * 128 + (((ks * 4 + quad) ^ low3) << 4));
  }
  __builtin_amdgcn_s_setprio(1);
#pragma unroll
  for (int ks = 0; ks < 2; ks++)
#pragma unroll
    for (int i = 0; i < 4; i++)
#pragma unroll
      for (int j = 0; j < 2; j++)
        acc[MH * 4 + i][NH * 2 + j] = __builtin_amdgcn_mfma_f32_16x16x32_bf16(
            af[i][ks], bv[j][ks], acc[MH * 4 + i][NH * 2 + j], 0, 0, 0);
  __builtin_amdgcn_s_setprio(0);
}

// register-transpose + convert + swizzled LDS write of one B K-tile slice
__device__ __forceinline__ void cvtwrB(const float4 (&L)[8], char* bbuf,
                                       int kc, int nb) {
  const float* lp = (const float*)&L[0];  // [r][jn] at lp[r*4+jn], unrolled
#pragma unroll
  for (int jn = 0; jn < 4; jn++) {
    int n_l = nb * 4 + jn;
    int slot = kc ^ (n_l & 7);
    unsigned u0, u1, u2, u3;
    asm("v_cvt_pk_bf16_f32 %0, %1, %2" : "=v"(u0) : "v"(lp[0 * 4 + jn]), "v"(lp[1 * 4 + jn]));
    asm("v_cvt_pk_bf16_f32 %0, %1, %2" : "=v"(u1) : "v"(lp[2 * 4 + jn]), "v"(lp[3 * 4 + jn]));
    asm("v_cvt_pk_bf16_f32 %0, %1, %2" : "=v"(u2) : "v"(lp[4 * 4 + jn]), "v"(lp[5 * 4 + jn]));
    asm("v_cvt_pk_bf16_f32 %0, %1, %2" : "=v"(u3) : "v"(lp[6 * 4 + jn]), "v"(lp[7 * 4 + jn]));
    uint4 wv;
    wv.x = u0; wv.y = u1; wv.z = u2; wv.w = u3;
    *(uint4*)(bbuf + n_l * 128 + slot * 16) = wv;
  }
}

template <int KDIM, int NDIM, bool FFN1>
__global__ __launch_bounds__(512, 2) void gemm_kernel(
    const short* __restrict__ A, const float* __restrict__ Wf,
    short* __restrict__ Hout, float* __restrict__ Out,
    const int* __restrict__ counts, const int* __restrict__ offsets,
    const int* __restrict__ tok_of_row, const float* __restrict__ gate_row,
    const int* __restrict__ tileE, const int* __restrict__ tileM,
    const int* __restrict__ ntiles) {
  constexpr int GX = NDIM / 256;
  constexpr int NWG = GX * MAX_TILES;
  static_assert(NWG % 8 == 0, "bijective XCD swizzle needs nwg%8==0");
  constexpr int Q = NWG / 8;
  int flat = blockIdx.y * GX + blockIdx.x;
  int wg = (flat & 7) * Q + (flat >> 3);  // XCD-chunked, bijective
  int ti = wg / GX;
  int nb_blk = wg - ti * GX;
  if (ti >= *ntiles) return;
  int e = tileE[ti], m0 = tileM[ti];
  int Me = counts[e], rowBase = offsets[e];
  int n0 = nb_blk * 256;

  // LDS: [A buf0 32K][A buf1 32K][B buf0 32K][B buf1 32K] = 128 KiB
  __shared__ __align__(1024) short lds[65536];

  int tid = threadIdx.x;
  int wid = tid >> 6, lane = tid & 63;
  int wm = wid >> 2, wn = wid & 3;

  // A staging: thread covers one 16B chunk; row rt = tid>>3, slot chunk
  // tid&7, swizzled source chunk cs.
  int rt = tid >> 3;
  int cs = (tid & 7) ^ (rt & 7);

  auto aPtr = [&](int mh, int s) {
    int r = m0 + mh * 128 + s * 64 + rt;
    if (r > Me - 1) r = Me - 1;  // clamp pad rows to a valid row
    size_t arow;
    if constexpr (FFN1)
      arow = (size_t)tok_of_row[rowBase + r];  // token-ordered Xbf
    else
      arow = (size_t)(rowBase + r);  // expert-sorted Hbuf
    return A + arow * KDIM + cs * 8;
  };
  const short* pA0a = aPtr(0, 0);
  const short* pA0b = aPtr(0, 1);
  const short* pA1a = aPtr(1, 0);
  const short* pA1b = aPtr(1, 1);

  // B staging: thread owns k-chunk kc (8 k) x 4 n, from f32 [k][n] source
  int kc = tid & 7;
  int nb = tid >> 3;  // 0..63 -> n = n0 + nb*4 .. +3
  const float* bSrc = Wf + (size_t)e * KDIM * NDIM + (size_t)(kc * 8) * NDIM +
                      n0 + nb * 4;

  floatx4 acc[8][4];
#pragma unroll
  for (int i = 0; i < 8; i++)
#pragma unroll
    for (int j = 0; j < 4; j++) acc[i][j] = floatx4{0.f, 0.f, 0.f, 0.f};

#define STAGEA(OFF)                                                 \
  load_lds16(pA0a, (char*)lds + (OFF) + wid * 1024);                \
  load_lds16(pA0b, (char*)lds + (OFF) + 8192 + wid * 1024);         \
  load_lds16(pA1a, (char*)lds + (OFF) + 16384 + wid * 1024);        \
  load_lds16(pA1b, (char*)lds + (OFF) + 16384 + 8192 + wid * 1024); \
  pA0a += 64;                                                       \
  pA0b += 64;                                                       \
  pA1a += 64;                                                       \
  pA1b += 64;

#define STAGEB()                                            \
  _Pragma("unroll") for (int r = 0; r < 8; r++) L[r] =      \
      *(const float4*)(bSrc + (size_t)r * NDIM);            \
  bSrc += (size_t)64 * NDIM;

  float4 L[8];
  // prologue: Breg(0), Agld(0); drain Breg only; write B(0) into buf0
  STAGEB()
  STAGEA(0)
  asm volatile("s_waitcnt vmcnt(4)" ::: "memory");
  cvtwrB(L, (char*)lds + 65536, kc, nb);

  constexpr int NT = KDIM / 64;
  int cur = 0;
  for (int t = 0; t < NT; ++t) {
    int nxt = cur ^ 1;
    const char* Ab = (const char*)lds + cur * 32768;
    const char* Bb = (const char*)lds + 65536 + cur * 32768;
    if (t + 1 < NT) {
      STAGEB()
      // drains Agld(t) (4 oldest); keeps Breg(t+1) 8 in flight
      asm volatile("s_waitcnt vmcnt(8) lgkmcnt(0)" ::: "memory");
    } else {
      asm volatile("s_waitcnt vmcnt(0) lgkmcnt(0)" ::: "memory");
    }
    __builtin_amdgcn_s_barrier();
    asm volatile("" ::: "memory");  // fence: nothing hoists above barrier
    if (t + 1 < NT) {
      STAGEA(nxt * 32768)  // safe: all waves past barrier -> done reading nxt
    }
    phase_mfma<0, 0>(Ab, Bb, acc, wm, wn, lane);
    phase_mfma<1, 0>(Ab, Bb, acc, wm, wn, lane);
    phase_mfma<0, 1>(Ab, Bb, acc, wm, wn, lane);
    phase_mfma<1, 1>(Ab, Bb, acc, wm, wn, lane);
    if (t + 1 < NT) {
      // drains Breg(t+1) (8 oldest); keeps Agld(t+1) 4 in flight
      asm volatile("s_waitcnt vmcnt(4)" ::: "memory");
      cvtwrB(L, (char*)lds + 65536 + nxt * 32768, kc, nb);
    }
    cur = nxt;
  }
#undef STAGEA
#undef STAGEB

  // epilogue. C/D layout: col = lane&15, row = (lane>>4)*4 + reg  [m89]
  int l15 = lane & 15;
#pragma unroll
  for (int i = 0; i < 8; i++) {
    int mb = (i >> 2) * 128 + wm * 64 + (i & 3) * 16 + ((lane >> 4) << 2);
#pragma unroll
    for (int r = 0; r < 4; r++) {
      int m = m0 + mb + r;
      if (m < Me) {
        int grow = rowBase + m;
        if constexpr (FFN1) {
#pragma unroll
          for (int j = 0; j < 4; j++) {
            float v = acc[i][j][r];
            v = v > 0.f ? v : 0.f;
            Hout[(size_t)grow * NDIM + n0 + (j >> 1) * 128 + wn * 32 +
                 (j & 1) * 16 + l15] = f2bf(v);
          }
        } else {
          int tk = tok_of_row[grow];
          float g = gate_row[grow];
#pragma unroll
          for (int j = 0; j < 4; j++)
            Out[(size_t)tk * NDIM + n0 + (j >> 1) * 128 + wn * 32 +
                (j & 1) * 16 + l15] = acc[i][j][r] * g;
        }
      }
    }
  }
}

extern "C" void kernel_launch(void* const* d_in, const int* in_sizes, int n_in,
                              void* d_out, int out_size, void* d_ws,
                              size_t ws_size, hipStream_t stream) {
  const float* x = (const float*)d_in[0];
  const float* w1 = (const float*)d_in[1];
  const float* w2 = (const float*)d_in[2];
  const float* rw = (const float*)d_in[3];
  const float* rb = (const float*)d_in[4];
  float* out = (float*)d_out;
  float* loss_out = out + (out_size - 1);  // loss scalar at tail

  char* ws = (char*)d_ws;
  size_t o = 0;
  auto alloc = [&](size_t bytes) {
    char* p = ws + o;
    o += (bytes + 255) & ~(size_t)255;
    return p;
  };
  short* Xbf = (short*)alloc((size_t)T_TOK * DDIM * 2);   // token-order x bf16
  short* Hbuf = (short*)alloc((size_t)T_TOK * FDIM * 2);  // relu(h) bf16
  int* tok_of_row = (int*)alloc(T_TOK * 4);
  float* gate_row = (float*)alloc(T_TOK * 4);
  int* expert_t = (int*)alloc(T_TOK * 4);
  float* gate_t = (float*)alloc(T_TOK * 4);
  int* counts = (int*)alloc(64);
  int* offsets = (int*)alloc(64);
  int* tileE = (int*)alloc(MAX_TILES * 4);
  int* tileM = (int*)alloc(MAX_TILES * 4);
  int* ntiles = (int*)alloc(64);

  // router: logits + gate + x->bf16
  router_kernel<<<T_TOK / 4, 256, 0, stream>>>(x, rw, rb, expert_t, gate_t,
                                               Xbf);
  // finalize: counts/offsets/tiles/loss + row scatter (small)
  finalize_kernel<<<1, 256, 0, stream>>>(expert_t, gate_t, counts, offsets,
                                         loss_out, tileE, tileM, ntiles,
                                         tok_of_row, gate_row);

  // FFN1: [n_e,1024] @ w1 f32 (fused transpose) -> relu -> Hbuf bf16
  gemm_kernel<DDIM, FDIM, true>
      <<<dim3(FDIM / 256, MAX_TILES), 512, 0, stream>>>(
          Xbf, w1, Hbuf, nullptr, counts, offsets, tok_of_row, nullptr, tileE,
          tileM, ntiles);
  // FFN2: [n_e,4096] @ w2 f32 (fused transpose) -> *gate -> scatter fp32
  gemm_kernel<FDIM, DDIM, false>
      <<<dim3(DDIM / 256, MAX_TILES), 512, 0, stream>>>(
          Hbuf, w2, nullptr, out, counts, offsets, tok_of_row, gate_row,
          tileE, tileM, ntiles);
}